// Round 12
// baseline (448.550 us; speedup 1.0000x reference)
//
#include <hip/hip_runtime.h>
#include <math.h>

typedef unsigned long long u64;
typedef unsigned short u16;
typedef __attribute__((ext_vector_type(8))) short bf16x8;
typedef __attribute__((ext_vector_type(4))) float f32x4;
typedef __attribute__((ext_vector_type(16))) float f32x16;

#define N_ANCH 2304
#define NP     2000
#define W1     36   // 2304/64
#define W2     32   // ceil(2000/64)

// ---------- output offsets (floats) ----------
#define O_RPN_LOGITS   0
#define O_RPN_DELTAS   4608
#define O_PROPOSALS    13824
#define O_ANCHORS      21824
#define O_RCNN_LOGITS  31040
#define O_RCNN_DELTAS  35040
#define O_RCNN_MASKS   43040
#define O_FINAL_DETS   435040
#define O_FINAL_MASKS  443040
#define O_FINAL_SCORES 835040
#define O_KEEP2        837040

__device__ __forceinline__ u16 f2bf(float f) {
    unsigned int x = __float_as_uint(f);
    unsigned int r = x + 0x7fffu + ((x >> 16) & 1u);   // RTNE
    return (u16)(r >> 16);
}

// ============================================================
// K1: backbone conv + relu -> feat [64,16,16] and feat_tf [pix][64]
// ============================================================
__global__ __launch_bounds__(256) void bb_conv(const float* __restrict__ x,
    const float* __restrict__ w, const float* __restrict__ b,
    float* __restrict__ feat, float* __restrict__ feat_tf)
{
    __shared__ __align__(16) float ws_[768];
    int c = blockIdx.x;
    for (int e = threadIdx.x; e < 192; e += 256)
        ((float4*)ws_)[e] = ((const float4*)(w + c*768))[e];
    __syncthreads();
    int fy = threadIdx.x >> 4, fx = threadIdx.x & 15;
    float acc = b[c];
    for (int ic = 0; ic < 3; ++ic)
        for (int ky = 0; ky < 16; ++ky) {
            const float* xr = x + (size_t)(ic*256 + fy*16+ky)*256 + fx*16;
            const float* wr = ws_ + ic*256 + ky*16;
            float xv[16];
            *(float4*)&xv[0]  = *(const float4*)(xr);
            *(float4*)&xv[4]  = *(const float4*)(xr+4);
            *(float4*)&xv[8]  = *(const float4*)(xr+8);
            *(float4*)&xv[12] = *(const float4*)(xr+12);
            #pragma unroll
            for (int kx = 0; kx < 16; ++kx) acc += xv[kx]*wr[kx];
        }
    float v = fmaxf(acc, 0.f);
    feat[c*256 + threadIdx.x] = v;
    feat_tf[threadIdx.x*64 + c] = v;
}

// ============================================================
// K2: RPN 3x3 SAME conv + relu -> h [64,16,16]
// 256 blocks = (channel, row-quarter); 6-row halo tile in LDS.
// Identical fmaf chain per output (ic, dy, dx ascending) -> bit-exact.
// ============================================================
__global__ __launch_bounds__(64) void rpn_conv(const float* __restrict__ feat,
    const float* __restrict__ w, const float* __restrict__ b, float* __restrict__ h)
{
    __shared__ __align__(16) float fl[64*6*16];     // [ic][slot][x], 24 KB
    __shared__ __align__(16) float ws_[576];
    int c = blockIdx.x;
    int q = blockIdx.y;                  // row quarter 0..3
    int r0 = q*4;
    int t = threadIdx.x;
    for (int e = t; e < 144; e += 64)
        ((float4*)ws_)[e] = ((const float4*)(w + c*576))[e];
    for (int e = t; e < 1536; e += 64) {
        int ic = e / 24, rem = e % 24, sl = rem >> 2, xq = rem & 3;
        int yg = r0 - 1 + sl;
        if ((unsigned)yg < 16u)
            ((float4*)fl)[ic*24 + sl*4 + xq] = ((const float4*)feat)[ic*64 + yg*4 + xq];
    }
    __syncthreads();
    int p = q*64 + t;
    int fy = p >> 4, fx = p & 15;
    float acc = b[c];
    for (int ic = 0; ic < 64; ++ic) {
        const float* fc = fl + ic*96;
        const float* wc = ws_ + ic*9;
        #pragma unroll
        for (int dy = 0; dy < 3; ++dy) {
            int y = fy + dy - 1;
            if (y < 0 || y > 15) continue;
            int sl = y - (r0 - 1);       // 0..5, staged
            #pragma unroll
            for (int dx = 0; dx < 3; ++dx) {
                int xx = fx + dx - 1;
                if (xx < 0 || xx > 15) continue;
                acc += fc[sl*16 + xx]*wc[dy*3 + dx];
            }
        }
    }
    h[c*256 + p] = fmaxf(acc, 0.f);
}

// ============================================================
// K3: RPN heads (1x1 convs) + softmax + anchors + decode + clip.
// 36 blocks x 64 threads; weights staged in LDS (identical arithmetic).
// ============================================================
__global__ __launch_bounds__(64) void heads_rpn(const float* __restrict__ hbuf,
    const float* __restrict__ w_cls, const float* __restrict__ b_cls,
    const float* __restrict__ w_box, const float* __restrict__ b_box,
    float* __restrict__ out_logits, float* __restrict__ out_deltas,
    float* __restrict__ out_anchors,
    float* __restrict__ scores, float* __restrict__ boxes)
{
    __shared__ __align__(16) float wcs[1152];
    __shared__ __align__(16) float wbs[2304];
    int t = threadIdx.x;
    for (int e = t; e < 288; e += 64) ((float4*)wcs)[e] = ((const float4*)w_cls)[e];
    for (int e = t; e < 576; e += 64) ((float4*)wbs)[e] = ((const float4*)w_box)[e];
    __syncthreads();
    int idx = blockIdx.x*64 + t;
    if (idx >= N_ANCH) return;
    int fy = idx / 144, r = idx % 144, fx = r / 9, a = r % 9;
    int pix = fy*16 + fx;
    float l0 = b_cls[a*2+0], l1 = b_cls[a*2+1];
    float d0 = b_box[a*4+0], d1 = b_box[a*4+1], d2 = b_box[a*4+2], d3 = b_box[a*4+3];
    const float* wc0 = wcs + (a*2+0)*64;
    const float* wc1 = wcs + (a*2+1)*64;
    const float* wb0 = wbs + (a*4+0)*64;
    const float* wb1 = wbs + (a*4+1)*64;
    const float* wb2 = wbs + (a*4+2)*64;
    const float* wb3 = wbs + (a*4+3)*64;
    for (int c = 0; c < 64; ++c) {
        float hv = hbuf[c*256 + pix];
        l0 += hv*wc0[c]; l1 += hv*wc1[c];
        d0 += hv*wb0[c]; d1 += hv*wb1[c]; d2 += hv*wb2[c]; d3 += hv*wb3[c];
    }
    out_logits[idx*2+0] = l0; out_logits[idx*2+1] = l1;
    out_deltas[idx*4+0] = d0; out_deltas[idx*4+1] = d1;
    out_deltas[idx*4+2] = d2; out_deltas[idx*4+3] = d3;
    float mx = fmaxf(l0,l1);
    float e0 = expf(l0-mx), e1 = expf(l1-mx);
    scores[idx] = e1/(e0+e1);
    float SC = (a/3 == 0) ? 32.f : ((a/3 == 1) ? 64.f : 128.f);
    float RT = (a%3 == 0) ? 0.5f : ((a%3 == 1) ? 1.f : 2.f);
    float wsz = SC*sqrtf(RT), hsz = SC/sqrtf(RT);
    float cx = (fx+0.5f)*16.f, cy = (fy+0.5f)*16.f;
    float ax1 = cx - wsz*0.5f, ay1 = cy - hsz*0.5f;
    float ax2 = cx + wsz*0.5f, ay2 = cy + hsz*0.5f;
    out_anchors[idx*4+0]=ax1; out_anchors[idx*4+1]=ay1;
    out_anchors[idx*4+2]=ax2; out_anchors[idx*4+3]=ay2;
    float aw = ax2-ax1, ah = ay2-ay1;
    float acx = ax1 + 0.5f*aw, acy = ay1 + 0.5f*ah;
    float ncx = acx + d0*aw, ncy = acy + d1*ah;
    float nw = aw*expf(d2), nh = ah*expf(d3);
    float x1 = ncx - 0.5f*nw, y1 = ncy - 0.5f*nh;
    float x2 = ncx + 0.5f*nw, y2 = ncy + 0.5f*nh;
    const float lim = 255.f;
    x1 = fminf(fmaxf(x1,0.f),lim); y1 = fminf(fmaxf(y1,0.f),lim);
    x2 = fminf(fmaxf(x2,0.f),lim); y2 = fminf(fmaxf(y2,0.f),lim);
    boxes[idx*4+0]=x1; boxes[idx*4+1]=y1; boxes[idx*4+2]=x2; boxes[idx*4+3]=y2;
}

// ============================================================
// stable descending argsort (matches jnp.argsort(-s)) -- parallel rank
// counting split over j-tiles. Integer partial counts sum exactly ->
// identical order to the serial version, bit-exact downstream.
// ============================================================
__global__ __launch_bounds__(256) void rank_part(const float* __restrict__ score,
    int* __restrict__ parts, int n)
{
    __shared__ __align__(16) float sj[256];
    int it = blockIdx.x, jt = blockIdx.y;
    int i = it*256 + threadIdx.x;
    int j0 = jt*256;
    int jj = j0 + threadIdx.x;
    sj[threadIdx.x] = (jj < n) ? score[jj] : 0.f;
    __syncthreads();
    if (i >= n) return;
    float si = score[i];
    int jmax = min(256, n - j0);
    int cnt = 0;
    const float4* s4 = (const float4*)sj;
    int q4 = jmax >> 2;           // jmax is 256 or 208 -> always /4
    for (int q = 0; q < q4; ++q) {
        float4 v = s4[q];
        int j = j0 + q*4;
        cnt += (v.x > si) || (v.x == si && (j+0) < i);
        cnt += (v.y > si) || (v.y == si && (j+1) < i);
        cnt += (v.z > si) || (v.z == si && (j+2) < i);
        cnt += (v.w > si) || (v.w == si && (j+3) < i);
    }
    parts[(size_t)jt*n + i] = cnt;
}

// rank_scatter fused with sorted-gather: writes order[r]=i AND the
// sorted box/area arrays directly (scatter instead of gather; same
// values, one fewer kernel).
__global__ __launch_bounds__(256) void rank_scatter_gather(const int* __restrict__ parts,
    const float4* __restrict__ boxes, int* __restrict__ order,
    float4* __restrict__ sb, float* __restrict__ sa, int n, int S)
{
    int i = blockIdx.x*256 + threadIdx.x;
    if (i >= n) return;
    int r = 0;
    for (int s = 0; s < S; ++s) r += parts[(size_t)s*n + i];
    order[r] = i;
    float4 bx = boxes[i];
    sb[r] = bx;
    sa[r] = fmaxf(bx.z-bx.x, 0.f)*fmaxf(bx.w-bx.y, 0.f);
}

// ============================================================
// IoU suppression bitmask (bits only for j > i); rows [n, ntotal) zeroed.
// Loads are unconditional (clamped) so the compiler can pipeline all 64;
// the mask condition is applied after -> identical bits.
// ============================================================
__global__ __launch_bounds__(256) void iou_mask(const float4* __restrict__ sb,
    const float* __restrict__ sa, int n, int ntotal, int words, float thr,
    u64* __restrict__ mask)
{
    int gid = blockIdx.x*256 + threadIdx.x;
    if (gid >= ntotal*words) return;
    int i = gid / words, w = gid % words;
    if (i >= n) { mask[(size_t)i*words + w] = 0; return; }
    float4 bi = sb[i]; float ai = sa[i];
    u64 m = 0;
    int j0 = w*64;
    #pragma unroll 8
    for (int bb = 0; bb < 64; ++bb) {
        int j = j0 + bb;
        int jc = min(j, n-1);
        float4 bj = sb[jc];
        float aj = sa[jc];
        float xx1 = fmaxf(bi.x, bj.x), yy1 = fmaxf(bi.y, bj.y);
        float xx2 = fminf(bi.z, bj.z), yy2 = fminf(bi.w, bj.w);
        float inter = fmaxf(xx2-xx1, 0.f)*fmaxf(yy2-yy1, 0.f);
        float iou = inter / (ai + aj - inter + 1e-8f);
        if (j > i && j < n && iou > thr) m |= 1ULL << bb;
    }
    mask[(size_t)i*words + w] = m;
}

// ============================================================
// workgroup-parallel blocked greedy NMS scan (256 threads).
// ============================================================
__global__ __launch_bounds__(256, 1) void nms_scan_wg(const u64* __restrict__ mask,
    int nblk, int words, u64* __restrict__ remout)
{
    __shared__ u64 rem_lds[64];
    __shared__ u64 diagS[64];
    __shared__ u64 pslot[8*64];
    int t = threadIdx.x;
    int ngrp = 256 / words;              // 36->7, 32->8
    int g = t / words, c = t % words;
    bool pactive = (g < ngrp);
    int gg = min(g, ngrp - 1);
    if (t < 64) {
        rem_lds[t] = ~0ULL;
        diagS[t] = mask[(size_t)t*words + 0];
    }
    __syncthreads();
    for (int b = 0; b < nblk; ++b) {
        const u64* blockbase = mask + (size_t)(64*b)*words;
        u64 vals[10];
        int rows[10];
        #pragma unroll
        for (int k = 0; k < 10; ++k) {
            int r = min(gg + k*ngrp, 63);
            rows[k] = r;
            vals[k] = blockbase[(size_t)r*words + c];
        }
        u64 dnext = mask[(size_t)(64*(b+1) + (t & 63))*words + min(b+1, words-1)];
        u64 mydia = diagS[t & 63];
        u64 nz = __ballot(mydia != 0ULL);
        u64 cur = rem_lds[b];
        u64 pend = cur & nz;
        unsigned mlo = (unsigned)mydia;
        unsigned mhi = (unsigned)(mydia >> 32);
        while (pend) {
            int i = __ffsll((unsigned long long)pend) - 1;
            unsigned lo = __builtin_amdgcn_readlane((int)mlo, i);
            unsigned hi = __builtin_amdgcn_readlane((int)mhi, i);
            u64 dia = ((u64)hi << 32) | lo;
            cur  &= ~dia;
            pend &= ~dia;
            pend &= pend - 1;
        }
        u64 partial = ~0ULL;
        #pragma unroll
        for (int k = 0; k < 10; ++k) {
            bool al = (cur >> rows[k]) & 1ULL;
            partial &= al ? ~vals[k] : ~0ULL;
        }
        if (pactive) pslot[g*64 + c] = partial;
        __syncthreads();
        if (t < 64) diagS[t] = dnext;
        if (t < words) {
            u64 red = rem_lds[t];
            for (int g2 = 0; g2 < ngrp; ++g2) red &= pslot[g2*64 + t];
            rem_lds[t] = red;
        }
        __syncthreads();
    }
    if (t < words) remout[t] = rem_lds[t];
}

// ============================================================
// kept-first stable selection -> proposals / valid. Also emits K (kept
// count) so downstream RoI-head kernels can skip duplicate zero-proposal
// rows (positions > K are all identical to position K's zero proposal).
// ============================================================
__global__ __launch_bounds__(256) void select_props(const u64* __restrict__ remw,
    const float4* __restrict__ sboxes, float* __restrict__ prop_out,
    float4* __restrict__ propws, int* __restrict__ validat, int* __restrict__ kcnt)
{
    __shared__ int cnt[256];
    __shared__ int pref[257];
    int t = threadIdx.x;
    int base = t*9;
    int c = 0;
    #pragma unroll
    for (int q = 0; q < 9; ++q) { int i = base+q; c += (int)((remw[i>>6]>>(i&63))&1ULL); }
    cnt[t] = c; __syncthreads();
    if (t == 0) { pref[0]=0; for (int u=0;u<256;u++) pref[u+1]=pref[u]+cnt[u]; }
    __syncthreads();
    int K = pref[256];
    if (t == 0) kcnt[0] = K;
    int kb = pref[t];
    int nb = K + (base - pref[t]);
    for (int q = 0; q < 9; ++q) {
        int i = base + q;
        int k = (int)((remw[i>>6]>>(i&63))&1ULL);
        int pos = k ? kb : nb;
        if (k) kb++; else nb++;
        if (pos < NP) {
            validat[pos] = k;
            float4 p = k ? sboxes[i] : make_float4(0.f,0.f,0.f,0.f);
            propws[pos] = p;
            prop_out[pos*4+0]=p.x; prop_out[pos*4+1]=p.y;
            prop_out[pos*4+2]=p.z; prop_out[pos*4+3]=p.w;
        }
    }
}

// ============================================================
// weight prep for 32x32x16 MFMA mask conv:
// wbt[((tap*4+kg)*2+half)*512 + oc*8 + e]  (bf16), ic = kg*16 + half*8 + e.
// ============================================================
__global__ __launch_bounds__(256) void prep_wbt(const float* __restrict__ w, u16* __restrict__ wbt)
{
    int e = blockIdx.x*256 + threadIdx.x;
    if (e >= 36864) return;
    int oc = e / 576, rem = e % 576, ic = rem / 9, tap = rem % 9;
    int kg = ic >> 4, half = (ic >> 3) & 1, el = ic & 7;
    wbt[((tap*4 + kg)*2 + half)*512 + oc*8 + el] = f2bf(w[e]);
}

// ============================================================
// K10: FUSED crop + 2x2 maxpool (-> flat, bit-exact f32) + MFMA mask head.
// Rows > K (duplicate zero proposals) are skipped; row K is the
// representative and its result is broadcast later (bit-exact).
// ============================================================
__global__ __launch_bounds__(256, 3) void mask_head_fused(const float* __restrict__ feat_tf,
    const float4* __restrict__ propws, const u16* __restrict__ wbt,
    const float* __restrict__ b_m1, const float* __restrict__ w_m2,
    const float* __restrict__ b_m2, float* __restrict__ masks_out,
    float* __restrict__ flat, const int* __restrict__ kcnt)
{
    __shared__ __align__(16) u16 crop[256*64];      // 32768 B
    __shared__ unsigned pooled[3136];               // 12544 B
    __shared__ __align__(16) int4 cidx[196];        //  3136 B
    __shared__ float2 cwt[196];                     //  1568 B
    __shared__ int2 cmeta[196];                     //  1568 B
    __shared__ __align__(16) float wm2s[64];        //   256 B
    __shared__ __align__(16) float b1s[64];         //   256 B  (total 52096)
    int n = blockIdx.x;
    if (n > *kcnt) return;
    int t = threadIdx.x;
    float4 p = propws[n];

    // zero-fill crop: lane-consecutive 16B stores, conflict-free
    #pragma unroll
    for (int k = 0; k < 8; ++k)
        *(int4*)(crop + k*2048 + t*8) = make_int4(0,0,0,0);
    for (int e = t; e < 3136; e += 256) pooled[e] = 0;
    if (t < 64) { wm2s[t] = w_m2[t]; b1s[t] = b_m1[t]; }
    if (t < 196) {
        float x1n = p.x*(1.f/255.f), y1n = p.y*(1.f/255.f);
        float x2n = p.z*(1.f/255.f), y2n = p.w*(1.f/255.f);
        int py = t / 14, px = t - py*14;
        float fyv = (y1n + (y2n-y1n)*(py*(1.f/13.f)))*15.f;
        float fxv = (x1n + (x2n-x1n)*(px*(1.f/13.f)))*15.f;
        int y0 = min(max((int)floorf(fyv),0),15), y1i = min(y0+1,15);
        int x0 = min(max((int)floorf(fxv),0),15), x1i = min(x0+1,15);
        float wy = fyv - (float)y0, wx = fxv - (float)x0;
        cidx[t] = make_int4((y0*16+x0)*64, (y0*16+x1i)*64, (y1i*16+x0)*64, (y1i*16+x1i)*64);
        cwt[t] = make_float2(wy, wx);
        cmeta[t] = make_int2((py+1)*16 + px + 1, (py>>1)*7 + (px>>1));
    }
    __syncthreads();

    int wave = t >> 6, lane = t & 63;
    for (int it = 0; it < 49; ++it) {
        int idx = it*4 + wave;                 // 0..195, wave-uniform
        int4 o4 = cidx[idx];
        float2 w2 = cwt[idx];
        int2 mt = cmeta[idx];
        float v00 = feat_tf[o4.x + lane];
        float v01 = feat_tf[o4.y + lane];
        float v10 = feat_tf[o4.z + lane];
        float v11 = feat_tf[o4.w + lane];
        float wy = w2.x, wx = w2.y;
        float top = v00*(1.f-wx) + v01*wx;
        float bot = v10*(1.f-wx) + v11*wx;
        float val = top*(1.f-wy) + bot*wy;
        int g = mt.x;
        crop[g*64 + (((lane>>3) ^ (g&7))<<3) + (lane&7)] = f2bf(val);
        atomicMax(&pooled[lane*49 + mt.y], __float_as_uint(val));
    }
    __syncthreads();

    // emit flat (bit-exact pooled max)
    {
        size_t rowoff = (size_t)n*3136;
        for (int k = t; k < 3136; k += 256)
            flat[rowoff + k] = __uint_as_float(pooled[k]);
    }

    // ---- MFMA conv: D[oc][pix], A = weights, B = crop ----
    int l31 = lane & 31, half = lane >> 5;
    int pix0 = wave*64 + l31, pix1 = pix0 + 32;

    f32x16 acc[2][2];   // [pixel tile][oc group]
    #pragma unroll
    for (int o = 0; o < 2; ++o) {
        #pragma unroll
        for (int q = 0; q < 4; ++q) {
            float4 b4 = *(const float4*)&b1s[o*32 + 4*half + 8*q];
            #pragma unroll
            for (int pp = 0; pp < 2; ++pp) {
                acc[pp][o][q*4+0] = b4.x; acc[pp][o][q*4+1] = b4.y;
                acc[pp][o][q*4+2] = b4.z; acc[pp][o][q*4+3] = b4.w;
            }
        }
    }

    for (int tap = 0; tap < 9; ++tap) {
        int doff = (tap/3 - 1)*16 + (tap%3) - 1;
        int p0 = (pix0 + doff) & 255;
        int p1 = (pix1 + doff) & 255;
        const u16* wt = wbt + tap*4096;
        bf16x8 af[2][4];
        #pragma unroll
        for (int kg = 0; kg < 4; ++kg) {
            #pragma unroll
            for (int o = 0; o < 2; ++o)
                af[o][kg] = *(const bf16x8*)(wt + (kg*2 + half)*512 + (o*32 + l31)*8);
        }
        int x0v = p0&7, x1v = p1&7;
        #pragma unroll
        for (int kg = 0; kg < 4; ++kg) {
            int slot = kg*2 + half;
            bf16x8 bf0 = *(const bf16x8*)(crop + p0*64 + ((slot ^ x0v)<<3));
            bf16x8 bf1 = *(const bf16x8*)(crop + p1*64 + ((slot ^ x1v)<<3));
            acc[0][0] = __builtin_amdgcn_mfma_f32_32x32x16_bf16(af[0][kg], bf0, acc[0][0], 0, 0, 0);
            acc[0][1] = __builtin_amdgcn_mfma_f32_32x32x16_bf16(af[1][kg], bf0, acc[0][1], 0, 0, 0);
            acc[1][0] = __builtin_amdgcn_mfma_f32_32x32x16_bf16(af[0][kg], bf1, acc[1][0], 0, 0, 0);
            acc[1][1] = __builtin_amdgcn_mfma_f32_32x32x16_bf16(af[1][kg], bf1, acc[1][1], 0, 0, 0);
        }
    }

    // ---- epilogue: relu, * w_m2[oc], sum over 64 oc, + b_m2 ----
    float4 wmq[2][4];
    #pragma unroll
    for (int o = 0; o < 2; ++o)
        #pragma unroll
        for (int q = 0; q < 4; ++q)
            wmq[o][q] = *(const float4*)&wm2s[o*32 + 4*half + 8*q];
    float s0 = 0.f, s1 = 0.f;
    #pragma unroll
    for (int o = 0; o < 2; ++o) {
        #pragma unroll
        for (int q = 0; q < 4; ++q) {
            float4 w4 = wmq[o][q];
            s0 = fmaf(fmaxf(acc[0][o][q*4+0], 0.f), w4.x, s0);
            s0 = fmaf(fmaxf(acc[0][o][q*4+1], 0.f), w4.y, s0);
            s0 = fmaf(fmaxf(acc[0][o][q*4+2], 0.f), w4.z, s0);
            s0 = fmaf(fmaxf(acc[0][o][q*4+3], 0.f), w4.w, s0);
            s1 = fmaf(fmaxf(acc[1][o][q*4+0], 0.f), w4.x, s1);
            s1 = fmaf(fmaxf(acc[1][o][q*4+1], 0.f), w4.y, s1);
            s1 = fmaf(fmaxf(acc[1][o][q*4+2], 0.f), w4.z, s1);
            s1 = fmaf(fmaxf(acc[1][o][q*4+3], 0.f), w4.w, s1);
        }
    }
    s0 += __shfl_xor(s0, 32);
    s1 += __shfl_xor(s1, 32);
    float sv = (half ? s1 : s0) + b_m2[0];
    int pw = half ? pix1 : pix0;
    int pyy = (pw>>4) - 1, pxx = (pw&15) - 1;
    if ((unsigned)pyy < 14u && (unsigned)pxx < 14u)
        masks_out[(size_t)n*196 + pyy*14 + pxx] = sv;
}

// ============================================================
// broadcast row K's RoI-head results into duplicate rows K+1..NP-1.
// Bit-exact: those rows have identical inputs (zero proposal).
// ============================================================
__global__ __launch_bounds__(256) void bcast_rows(const int* __restrict__ kcnt,
    float* __restrict__ out_logits, float* __restrict__ out_deltas,
    float* __restrict__ masks_out, float4* __restrict__ dets,
    float* __restrict__ dscores, float* __restrict__ s2)
{
    int K = *kcnt;
    int j = blockIdx.x;
    if (j <= K) return;
    int t = threadIdx.x;
    if (t < 196) {
        masks_out[(size_t)j*196 + t] = masks_out[(size_t)K*196 + t];
    } else if (t == 196) {
        out_logits[j*2+0] = out_logits[K*2+0];
        out_logits[j*2+1] = out_logits[K*2+1];
    } else if (t == 197) {
        out_deltas[j*4+0] = out_deltas[K*4+0];
        out_deltas[j*4+1] = out_deltas[K*4+1];
        out_deltas[j*4+2] = out_deltas[K*4+2];
        out_deltas[j*4+3] = out_deltas[K*4+3];
    } else if (t == 198) {
        dets[j] = dets[K];
        dscores[j] = dscores[K];
        s2[j] = s2[K];
    }
}

// ============================================================
// f32 GEMM partial over K-split — single-wave 32x16 tile, 64 threads,
// BK=32, named prefetch regs. Halved N-tile doubles active waves
// (~2.2/SIMD) for latency hiding; per-output fmaf chain is the same
// ascending-k sequence as the 32x32 version -> partials bit-identical.
// XCD swizzle: 4 col tiles per XCD (bijective). Rows > kcnt exit.
// ============================================================
__global__ __launch_bounds__(64) void gemm_f32_w1(const float* __restrict__ A,
    const float* __restrict__ B, float* __restrict__ Cpart,
    int M, int N, int K, int Kblk, const int* __restrict__ kcnt)
{
    int flat = blockIdx.x + blockIdx.y*gridDim.x;        // launch order, x fastest
    int colt = ((flat & 7) << 2) | ((flat >> 3) & 3);    // 32 cols, 4 per XCD
    int rowt = flat >> 5;                                // 0..62
    int row0 = rowt*32, col0 = colt*16;
    if (row0 > *kcnt) return;
    __shared__ __align__(16) float As[32][36];
    __shared__ __align__(16) float Bs[32][20];
    int s = blockIdx.z;
    int kbase = s*Kblk;
    int t = threadIdx.x;

    // staging maps (64 threads)
    int arow = t >> 1;            // 0..31
    int kh   = (t & 1) * 16;      // 0 or 16
    int am = min(row0 + arow, M-1);
    const float* Arow = A + (size_t)am*K + kbase + kh;
    int bk = t & 31;              // 0..31
    int ch = (t >> 5) * 8;        // 0 or 8
    const float* Bbase = B + (size_t)(kbase + bk)*N + col0 + ch;

    // compute map: 8 row-groups x 8 col-groups; 4x2 outputs each
    int cx = t & 7, ry = (t >> 3) & 7;
    int rbase = ry*4, cbase = cx*2;

    float4 pa0 = *(const float4*)(Arow);
    float4 pa1 = *(const float4*)(Arow + 4);
    float4 pa2 = *(const float4*)(Arow + 8);
    float4 pa3 = *(const float4*)(Arow + 12);
    float4 pb0 = *(const float4*)(Bbase);
    float4 pb1 = *(const float4*)(Bbase + 4);

    float acc[4][2] = {};
    for (int k0 = 0; k0 < Kblk; k0 += 32) {
        As[kh+ 0][arow]=pa0.x; As[kh+ 1][arow]=pa0.y; As[kh+ 2][arow]=pa0.z; As[kh+ 3][arow]=pa0.w;
        As[kh+ 4][arow]=pa1.x; As[kh+ 5][arow]=pa1.y; As[kh+ 6][arow]=pa1.z; As[kh+ 7][arow]=pa1.w;
        As[kh+ 8][arow]=pa2.x; As[kh+ 9][arow]=pa2.y; As[kh+10][arow]=pa2.z; As[kh+11][arow]=pa2.w;
        As[kh+12][arow]=pa3.x; As[kh+13][arow]=pa3.y; As[kh+14][arow]=pa3.z; As[kh+15][arow]=pa3.w;
        *(float4*)&Bs[bk][ch]    = pb0;
        *(float4*)&Bs[bk][ch+4]  = pb1;
        __syncthreads();
        int kn = k0 + 32;
        if (kn < Kblk) {
            pa0 = *(const float4*)(Arow + kn);
            pa1 = *(const float4*)(Arow + kn + 4);
            pa2 = *(const float4*)(Arow + kn + 8);
            pa3 = *(const float4*)(Arow + kn + 12);
            const float* Bn = Bbase + (size_t)kn*N;
            pb0 = *(const float4*)(Bn);
            pb1 = *(const float4*)(Bn + 4);
        }
        #pragma unroll
        for (int k = 0; k < 32; ++k) {
            float4 av = *(float4*)&As[k][rbase];
            float b0 = Bs[k][cbase], b1 = Bs[k][cbase+1];
            acc[0][0] = fmaf(av.x, b0, acc[0][0]);
            acc[0][1] = fmaf(av.x, b1, acc[0][1]);
            acc[1][0] = fmaf(av.y, b0, acc[1][0]);
            acc[1][1] = fmaf(av.y, b1, acc[1][1]);
            acc[2][0] = fmaf(av.z, b0, acc[2][0]);
            acc[2][1] = fmaf(av.z, b1, acc[2][1]);
            acc[3][0] = fmaf(av.w, b0, acc[3][0]);
            acc[3][1] = fmaf(av.w, b1, acc[3][1]);
        }
        __syncthreads();
    }
    float* Cp = Cpart + (size_t)s*M*N;
    #pragma unroll
    for (int i = 0; i < 4; ++i) {
        int gm = row0 + rbase + i;
        if (gm >= M) continue;
        int gn = col0 + cbase;
        Cp[(size_t)gm*N + gn]     = acc[i][0];
        Cp[(size_t)gm*N + gn + 1] = acc[i][1];
    }
}

// ============================================================
// combine K-split partials in ascending-s order + bias + optional relu.
// Rows above kcnt skipped (duplicate rows, never consumed).
// ============================================================
__global__ __launch_bounds__(256) void combine_parts(const float* __restrict__ parts,
    const float* __restrict__ bias, float* __restrict__ C,
    int MN, int N, int S, int relu, const int* __restrict__ kcnt)
{
    int i4 = blockIdx.x*256 + threadIdx.x;
    if (i4*4 >= MN) return;
    size_t idx = (size_t)i4*4;
    if ((int)(idx / (unsigned)N) > *kcnt) return;
    float4 acc = *(const float4*)(parts + idx);
    for (int s = 1; s < S; ++s) {
        float4 v = *(const float4*)(parts + (size_t)s*MN + idx);
        acc.x += v.x; acc.y += v.y; acc.z += v.z; acc.w += v.w;
    }
    int nb = (int)(idx & (N-1));
    float4 bv = *(const float4*)(bias + nb);
    acc.x += bv.x; acc.y += bv.y; acc.z += bv.z; acc.w += bv.w;
    if (relu) {
        acc.x = fmaxf(acc.x, 0.f); acc.y = fmaxf(acc.y, 0.f);
        acc.z = fmaxf(acc.z, 0.f); acc.w = fmaxf(acc.w, 0.f);
    }
    *(float4*)(C + idx) = acc;
}

// ============================================================
// K9: rcnn heads — coalesced LDS staging, then 8 serial threads replay
// the sequential fmaf chain bit-exactly. Blocks fully above kcnt skip.
// ============================================================
__global__ __launch_bounds__(256) void rcnn_heads_lds(const float* __restrict__ h2,
    const float* __restrict__ w_rcls, const float* __restrict__ b_rcls,
    const float* __restrict__ w_rbox, const float* __restrict__ b_rbox,
    const float4* __restrict__ propws, const int* __restrict__ validat,
    float* __restrict__ out_logits, float* __restrict__ out_deltas,
    float4* __restrict__ dets, float* __restrict__ dscores, float* __restrict__ s2,
    const int* __restrict__ kcnt)
{
    int b0 = blockIdx.x*8;
    if (b0 > *kcnt) return;
    __shared__ float hs[8*520];
    for (int e = threadIdx.x; e < 8*512; e += 256) {
        int pr = e >> 9, k = e & 511;
        hs[pr*520 + k] = h2[(size_t)(b0+pr)*512 + k];
    }
    __syncthreads();
    int t = threadIdx.x;
    if (t >= 8) return;
    int n = b0 + t;
    const float* hv = hs + t*520;
    float l0 = b_rcls[0], l1 = b_rcls[1];
    float d0 = b_rbox[0], d1 = b_rbox[1], d2 = b_rbox[2], d3 = b_rbox[3];
    for (int k = 0; k < 512; ++k) {
        float v = hv[k];
        l0 = fmaf(v, w_rcls[k*2+0], l0); l1 = fmaf(v, w_rcls[k*2+1], l1);
        d0 = fmaf(v, w_rbox[k*4+0], d0); d1 = fmaf(v, w_rbox[k*4+1], d1);
        d2 = fmaf(v, w_rbox[k*4+2], d2); d3 = fmaf(v, w_rbox[k*4+3], d3);
    }
    out_logits[n*2+0]=l0; out_logits[n*2+1]=l1;
    out_deltas[n*4+0]=d0; out_deltas[n*4+1]=d1;
    out_deltas[n*4+2]=d2; out_deltas[n*4+3]=d3;
    float mx = fmaxf(l0,l1);
    float e0 = expf(l0-mx), e1 = expf(l1-mx);
    float sc = e1/(e0+e1);
    float4 p = propws[n];
    float w = p.z-p.x, h = p.w-p.y;
    float cx = p.x + 0.5f*w, cy = p.y + 0.5f*h;
    float ncx = cx + d0*w, ncy = cy + d1*h;
    float nw = w*expf(d2), nh = h*expf(d3);
    float x1 = ncx-0.5f*nw, y1 = ncy-0.5f*nh, x2 = ncx+0.5f*nw, y2 = ncy+0.5f*nh;
    const float lim = 255.f;
    x1 = fminf(fmaxf(x1,0.f),lim); y1 = fminf(fmaxf(y1,0.f),lim);
    x2 = fminf(fmaxf(x2,0.f),lim); y2 = fminf(fmaxf(y2,0.f),lim);
    dets[n] = make_float4(x1,y1,x2,y2);
    dscores[n] = sc;
    s2[n] = validat[n] ? sc : -1.0f;
}

// ============================================================
// final outputs
// ============================================================
__global__ void finalize(const u64* __restrict__ remw2,
    const int* __restrict__ order2, const int* __restrict__ validat,
    const float4* __restrict__ dets, const float* __restrict__ dscores,
    const float* __restrict__ masks_in, float* __restrict__ fdets,
    float* __restrict__ fscores, float* __restrict__ fmasks, float* __restrict__ keep2out)
{
    int j = blockIdx.x;
    int t = threadIdx.x;
    int o = order2[j];
    int kb = (int)((remw2[j>>6] >> (j&63)) & 1ULL);
    int k2 = kb & validat[o];
    if (t == 0) {
        float4 d = dets[o];
        if (!k2) d = make_float4(0.f,0.f,0.f,0.f);
        fdets[j*4+0]=d.x; fdets[j*4+1]=d.y; fdets[j*4+2]=d.z; fdets[j*4+3]=d.w;
        fscores[j] = k2 ? dscores[o] : 0.f;
        keep2out[j] = (float)k2;
    }
    if (t < 196) {
        float mv = masks_in[(size_t)o*196 + t];
        float sg = 1.f/(1.f + expf(-mv));
        fmasks[(size_t)j*196 + t] = k2 ? sg : 0.f;
    }
}

// ============================================================
extern "C" void kernel_launch(void* const* d_in, const int* in_sizes, int n_in,
                              void* d_out, int out_size, void* d_ws, size_t ws_size,
                              hipStream_t stream)
{
    const float* x      = (const float*)d_in[0];
    const float* w_bb   = (const float*)d_in[1];
    const float* b_bb   = (const float*)d_in[2];
    const float* w_rpn  = (const float*)d_in[3];
    const float* b_rpn  = (const float*)d_in[4];
    const float* w_cls  = (const float*)d_in[5];
    const float* b_cls  = (const float*)d_in[6];
    const float* w_box  = (const float*)d_in[7];
    const float* b_box  = (const float*)d_in[8];
    const float* w_fc1  = (const float*)d_in[9];
    const float* b_fc1  = (const float*)d_in[10];
    const float* w_fc2  = (const float*)d_in[11];
    const float* b_fc2  = (const float*)d_in[12];
    const float* w_rcls = (const float*)d_in[13];
    const float* b_rcls = (const float*)d_in[14];
    const float* w_rbox = (const float*)d_in[15];
    const float* b_rbox = (const float*)d_in[16];
    const float* w_m1   = (const float*)d_in[17];
    const float* b_m1   = (const float*)d_in[18];
    const float* w_m2   = (const float*)d_in[19];
    const float* b_m2   = (const float*)d_in[20];

    float* out = (float*)d_out;

    // ---- workspace carve-up (256B-aligned chunks) ----
    char* basep = (char*)d_ws;
    auto alloc = [&](size_t bytes) { char* q = basep; basep += (bytes + 255) & ~(size_t)255; return q; };
    float* feat    = (float*)alloc(16384*4);
    float* feat_tf = (float*)alloc(16384*4);
    float* hbuf    = (float*)alloc(16384*4);
    float* scores  = (float*)alloc(2304*4);
    float* boxes   = (float*)alloc(9216*4);
    int*   order1  = (int*)  alloc(2304*4);
    int*   rparts  = (int*)  alloc((size_t)9*2304*4);
    float* sboxes  = (float*)alloc(9216*4);
    float* sareas  = (float*)alloc(2304*4);
    u64*   supm1   = (u64*)  alloc((size_t)((W1+1)*64)*W1*8);   // +64 slack rows
    u64*   remw1   = (u64*)  alloc(W1*8);
    int*   validat = (int*)  alloc(NP*4);
    float* propws  = (float*)alloc(NP*4*4);
    int*   kcnt    = (int*)  alloc(4);
    u16*   wbt     = (u16*)  alloc(36864*2);
    float* flat    = (float*)alloc((size_t)NP*3136*4);
    float* h1      = (float*)alloc((size_t)NP*512*4);
    float* h2      = (float*)alloc((size_t)NP*512*4);
    float* gparts  = (float*)alloc((size_t)7*NP*512*4);     // K-split partials
    float* dets    = (float*)alloc(NP*4*4);
    float* dscores = (float*)alloc(NP*4);
    float* s2      = (float*)alloc(NP*4);
    int*   order2  = (int*)  alloc(NP*4);
    float* sdets   = (float*)alloc(NP*4*4);
    float* sareas2 = (float*)alloc(NP*4);
    u64*   supm2   = (u64*)  alloc((size_t)((W2+1)*64)*W2*8);   // +64 slack rows
    u64*   remw2   = (u64*)  alloc(W2*8);

    // ---- stage 1: backbone + rpn ----
    bb_conv<<<64, 256, 0, stream>>>(x, w_bb, b_bb, feat, feat_tf);
    rpn_conv<<<dim3(64, 4), 64, 0, stream>>>(feat, w_rpn, b_rpn, hbuf);
    heads_rpn<<<36, 64, 0, stream>>>(hbuf, w_cls, b_cls, w_box, b_box,
        out + O_RPN_LOGITS, out + O_RPN_DELTAS, out + O_ANCHORS, scores, boxes);

    // ---- NMS 1 ----
    rank_part<<<dim3(9, 9), 256, 0, stream>>>(scores, rparts, N_ANCH);
    rank_scatter_gather<<<9, 256, 0, stream>>>(rparts, (const float4*)boxes,
        order1, (float4*)sboxes, sareas, N_ANCH, 9);
    iou_mask<<<(W1*64*W1+255)/256, 256, 0, stream>>>((const float4*)sboxes, sareas,
                                                     N_ANCH, W1*64, W1, 0.5f, supm1);
    nms_scan_wg<<<1, 256, 0, stream>>>(supm1, W1, W1, remw1);
    select_props<<<1, 256, 0, stream>>>(remw1, (const float4*)sboxes,
                                        out + O_PROPOSALS, (float4*)propws, validat, kcnt);

    // ---- weight prep (independent of NMS; early) ----
    prep_wbt<<<144, 256, 0, stream>>>(w_m1, wbt);

    // ---- RoI head: fused crop+pool+mask first (produces flat) ----
    mask_head_fused<<<NP, 256, 0, stream>>>(feat_tf, (const float4*)propws, wbt,
        b_m1, w_m2, b_m2, out + O_RCNN_MASKS, flat, kcnt);
    // fc1: K=3136 split 7 x 448; single-wave 32x16 tiles (2x waves), XCD swizzle
    gemm_f32_w1<<<dim3(63, 32, 7), 64, 0, stream>>>(flat, w_fc1, gparts,
                                                    NP, 512, 3136, 448, kcnt);
    combine_parts<<<(NP*512/4+255)/256, 256, 0, stream>>>(gparts, b_fc1, h1,
                                                          NP*512, 512, 7, 1, kcnt);
    // fc2: K=512 split 2 x 256
    gemm_f32_w1<<<dim3(63, 32, 2), 64, 0, stream>>>(h1, w_fc2, gparts,
                                                    NP, 512, 512, 256, kcnt);
    combine_parts<<<(NP*512/4+255)/256, 256, 0, stream>>>(gparts, b_fc2, h2,
                                                          NP*512, 512, 2, 1, kcnt);
    rcnn_heads_lds<<<250, 256, 0, stream>>>(h2, w_rcls, b_rcls, w_rbox, b_rbox,
        (const float4*)propws, validat, out + O_RCNN_LOGITS, out + O_RCNN_DELTAS,
        (float4*)dets, dscores, s2, kcnt);

    // ---- broadcast duplicate rows (bit-exact) before NMS2 consumes them ----
    bcast_rows<<<NP, 256, 0, stream>>>(kcnt, out + O_RCNN_LOGITS, out + O_RCNN_DELTAS,
        out + O_RCNN_MASKS, (float4*)dets, dscores, s2);

    // ---- NMS 2 + finalize ----
    rank_part<<<dim3(8, 8), 256, 0, stream>>>(s2, rparts, NP);
    rank_scatter_gather<<<8, 256, 0, stream>>>(rparts, (const float4*)dets,
        order2, (float4*)sdets, sareas2, NP, 8);
    iou_mask<<<(W2*64*W2+255)/256, 256, 0, stream>>>((const float4*)sdets, sareas2,
                                                     NP, W2*64, W2, 0.3f, supm2);
    nms_scan_wg<<<1, 256, 0, stream>>>(supm2, W2, W2, remw2);
    finalize<<<NP, 256, 0, stream>>>(remw2, order2, validat, (const float4*)dets,
        dscores, out + O_RCNN_MASKS, out + O_FINAL_DETS, out + O_FINAL_SCORES,
        out + O_FINAL_MASKS, out + O_KEEP2);
}

// Round 13
// 434.163 us; speedup vs baseline: 1.0331x; 1.0331x over previous
//
#include <hip/hip_runtime.h>
#include <math.h>

typedef unsigned long long u64;
typedef unsigned short u16;
typedef __attribute__((ext_vector_type(8))) short bf16x8;
typedef __attribute__((ext_vector_type(4))) float f32x4;
typedef __attribute__((ext_vector_type(16))) float f32x16;

#define N_ANCH 2304
#define NP     2000
#define W1     36   // 2304/64
#define W2     32   // ceil(2000/64)

// ---------- output offsets (floats) ----------
#define O_RPN_LOGITS   0
#define O_RPN_DELTAS   4608
#define O_PROPOSALS    13824
#define O_ANCHORS      21824
#define O_RCNN_LOGITS  31040
#define O_RCNN_DELTAS  35040
#define O_RCNN_MASKS   43040
#define O_FINAL_DETS   435040
#define O_FINAL_MASKS  443040
#define O_FINAL_SCORES 835040
#define O_KEEP2        837040

__device__ __forceinline__ u16 f2bf(float f) {
    unsigned int x = __float_as_uint(f);
    unsigned int r = x + 0x7fffu + ((x >> 16) & 1u);   // RTNE
    return (u16)(r >> 16);
}

// ============================================================
// K1: backbone conv + relu -> feat [64,16,16] and feat_tf [pix][64]
// ============================================================
__global__ __launch_bounds__(256) void bb_conv(const float* __restrict__ x,
    const float* __restrict__ w, const float* __restrict__ b,
    float* __restrict__ feat, float* __restrict__ feat_tf)
{
    __shared__ __align__(16) float ws_[768];
    int c = blockIdx.x;
    for (int e = threadIdx.x; e < 192; e += 256)
        ((float4*)ws_)[e] = ((const float4*)(w + c*768))[e];
    __syncthreads();
    int fy = threadIdx.x >> 4, fx = threadIdx.x & 15;
    float acc = b[c];
    for (int ic = 0; ic < 3; ++ic)
        for (int ky = 0; ky < 16; ++ky) {
            const float* xr = x + (size_t)(ic*256 + fy*16+ky)*256 + fx*16;
            const float* wr = ws_ + ic*256 + ky*16;
            float xv[16];
            *(float4*)&xv[0]  = *(const float4*)(xr);
            *(float4*)&xv[4]  = *(const float4*)(xr+4);
            *(float4*)&xv[8]  = *(const float4*)(xr+8);
            *(float4*)&xv[12] = *(const float4*)(xr+12);
            #pragma unroll
            for (int kx = 0; kx < 16; ++kx) acc += xv[kx]*wr[kx];
        }
    float v = fmaxf(acc, 0.f);
    feat[c*256 + threadIdx.x] = v;
    feat_tf[threadIdx.x*64 + c] = v;
}

// ============================================================
// K2: RPN 3x3 SAME conv + relu -> h [64,16,16]
// ============================================================
__global__ __launch_bounds__(256) void rpn_conv(const float* __restrict__ feat,
    const float* __restrict__ w, const float* __restrict__ b, float* __restrict__ h)
{
    __shared__ __align__(16) float f[16384];
    __shared__ __align__(16) float ws_[576];
    int c = blockIdx.x;
    for (int e = threadIdx.x; e < 4096; e += 256)
        ((float4*)f)[e] = ((const float4*)feat)[e];
    for (int e = threadIdx.x; e < 144; e += 256)
        ((float4*)ws_)[e] = ((const float4*)(w + c*576))[e];
    __syncthreads();
    int fy = threadIdx.x >> 4, fx = threadIdx.x & 15;
    float acc = b[c];
    for (int ic = 0; ic < 64; ++ic) {
        const float* fc = f + ic*256;
        const float* wc = ws_ + ic*9;
        #pragma unroll
        for (int dy = 0; dy < 3; ++dy) {
            int y = fy + dy - 1;
            if (y < 0 || y > 15) continue;
            #pragma unroll
            for (int dx = 0; dx < 3; ++dx) {
                int xx = fx + dx - 1;
                if (xx < 0 || xx > 15) continue;
                acc += fc[y*16+xx]*wc[dy*3+dx];
            }
        }
    }
    h[c*256 + threadIdx.x] = fmaxf(acc, 0.f);
}

// ============================================================
// K3: RPN heads (1x1 convs) + softmax + anchors + decode + clip
// ============================================================
__global__ __launch_bounds__(256) void heads_rpn(const float* __restrict__ hbuf,
    const float* __restrict__ w_cls, const float* __restrict__ b_cls,
    const float* __restrict__ w_box, const float* __restrict__ b_box,
    float* __restrict__ out_logits, float* __restrict__ out_deltas,
    float* __restrict__ out_anchors,
    float* __restrict__ scores, float* __restrict__ boxes)
{
    int idx = blockIdx.x*256 + threadIdx.x;
    if (idx >= N_ANCH) return;
    int fy = idx / 144, r = idx % 144, fx = r / 9, a = r % 9;
    int pix = fy*16 + fx;
    float l0 = b_cls[a*2+0], l1 = b_cls[a*2+1];
    float d0 = b_box[a*4+0], d1 = b_box[a*4+1], d2 = b_box[a*4+2], d3 = b_box[a*4+3];
    const float* wc0 = w_cls + (a*2+0)*64;
    const float* wc1 = w_cls + (a*2+1)*64;
    const float* wb0 = w_box + (a*4+0)*64;
    const float* wb1 = w_box + (a*4+1)*64;
    const float* wb2 = w_box + (a*4+2)*64;
    const float* wb3 = w_box + (a*4+3)*64;
    for (int c = 0; c < 64; ++c) {
        float hv = hbuf[c*256 + pix];
        l0 += hv*wc0[c]; l1 += hv*wc1[c];
        d0 += hv*wb0[c]; d1 += hv*wb1[c]; d2 += hv*wb2[c]; d3 += hv*wb3[c];
    }
    out_logits[idx*2+0] = l0; out_logits[idx*2+1] = l1;
    out_deltas[idx*4+0] = d0; out_deltas[idx*4+1] = d1;
    out_deltas[idx*4+2] = d2; out_deltas[idx*4+3] = d3;
    float mx = fmaxf(l0,l1);
    float e0 = expf(l0-mx), e1 = expf(l1-mx);
    scores[idx] = e1/(e0+e1);
    float SC = (a/3 == 0) ? 32.f : ((a/3 == 1) ? 64.f : 128.f);
    float RT = (a%3 == 0) ? 0.5f : ((a%3 == 1) ? 1.f : 2.f);
    float wsz = SC*sqrtf(RT), hsz = SC/sqrtf(RT);
    float cx = (fx+0.5f)*16.f, cy = (fy+0.5f)*16.f;
    float ax1 = cx - wsz*0.5f, ay1 = cy - hsz*0.5f;
    float ax2 = cx + wsz*0.5f, ay2 = cy + hsz*0.5f;
    out_anchors[idx*4+0]=ax1; out_anchors[idx*4+1]=ay1;
    out_anchors[idx*4+2]=ax2; out_anchors[idx*4+3]=ay2;
    float aw = ax2-ax1, ah = ay2-ay1;
    float acx = ax1 + 0.5f*aw, acy = ay1 + 0.5f*ah;
    float ncx = acx + d0*aw, ncy = acy + d1*ah;
    float nw = aw*expf(d2), nh = ah*expf(d3);
    float x1 = ncx - 0.5f*nw, y1 = ncy - 0.5f*nh;
    float x2 = ncx + 0.5f*nw, y2 = ncy + 0.5f*nh;
    const float lim = 255.f;
    x1 = fminf(fmaxf(x1,0.f),lim); y1 = fminf(fmaxf(y1,0.f),lim);
    x2 = fminf(fmaxf(x2,0.f),lim); y2 = fminf(fmaxf(y2,0.f),lim);
    boxes[idx*4+0]=x1; boxes[idx*4+1]=y1; boxes[idx*4+2]=x2; boxes[idx*4+3]=y2;
}

// ============================================================
// stable descending argsort (matches jnp.argsort(-s)) -- parallel rank
// counting split over j-tiles. Integer partial counts sum exactly ->
// identical order to the serial version, bit-exact downstream.
// ============================================================
__global__ __launch_bounds__(256) void rank_part(const float* __restrict__ score,
    int* __restrict__ parts, int n)
{
    __shared__ __align__(16) float sj[256];
    int it = blockIdx.x, jt = blockIdx.y;
    int i = it*256 + threadIdx.x;
    int j0 = jt*256;
    int jj = j0 + threadIdx.x;
    sj[threadIdx.x] = (jj < n) ? score[jj] : 0.f;
    __syncthreads();
    if (i >= n) return;
    float si = score[i];
    int jmax = min(256, n - j0);
    int cnt = 0;
    const float4* s4 = (const float4*)sj;
    int q4 = jmax >> 2;           // jmax is 256 or 208 -> always /4
    for (int q = 0; q < q4; ++q) {
        float4 v = s4[q];
        int j = j0 + q*4;
        cnt += (v.x > si) || (v.x == si && (j+0) < i);
        cnt += (v.y > si) || (v.y == si && (j+1) < i);
        cnt += (v.z > si) || (v.z == si && (j+2) < i);
        cnt += (v.w > si) || (v.w == si && (j+3) < i);
    }
    parts[(size_t)jt*n + i] = cnt;
}

__global__ __launch_bounds__(256) void rank_scatter(const int* __restrict__ parts,
    int* __restrict__ order, int n, int S)
{
    int i = blockIdx.x*256 + threadIdx.x;
    if (i >= n) return;
    int r = 0;
    for (int s = 0; s < S; ++s) r += parts[(size_t)s*n + i];
    order[r] = i;
}

__global__ __launch_bounds__(256) void gather_sorted(const float4* __restrict__ boxes,
    const int* __restrict__ order, float4* __restrict__ sb, float* __restrict__ sa, int n)
{
    int i = blockIdx.x*256 + threadIdx.x;
    if (i >= n) return;
    float4 b = boxes[order[i]];
    sb[i] = b;
    sa[i] = fmaxf(b.z-b.x, 0.f)*fmaxf(b.w-b.y, 0.f);
}

// ============================================================
// IoU suppression bitmask (bits only for j > i); rows [n, ntotal) zeroed
// ============================================================
__global__ __launch_bounds__(256) void iou_mask(const float4* __restrict__ sb,
    const float* __restrict__ sa, int n, int ntotal, int words, float thr,
    u64* __restrict__ mask)
{
    int gid = blockIdx.x*256 + threadIdx.x;
    if (gid >= ntotal*words) return;
    int i = gid / words, w = gid % words;
    if (i >= n) { mask[(size_t)i*words + w] = 0; return; }
    float4 bi = sb[i]; float ai = sa[i];
    u64 m = 0;
    int j0 = w*64;
    for (int bb = 0; bb < 64; ++bb) {
        int j = j0 + bb;
        if (j > i && j < n) {
            float4 bj = sb[j];
            float xx1 = fmaxf(bi.x, bj.x), yy1 = fmaxf(bi.y, bj.y);
            float xx2 = fminf(bi.z, bj.z), yy2 = fminf(bi.w, bj.w);
            float inter = fmaxf(xx2-xx1, 0.f)*fmaxf(yy2-yy1, 0.f);
            float iou = inter / (ai + sa[j] - inter + 1e-8f);
            if (iou > thr) m |= 1ULL << bb;
        }
    }
    mask[(size_t)i*words + w] = m;
}

// ============================================================
// workgroup-parallel blocked greedy NMS scan (256 threads).
// ============================================================
__global__ __launch_bounds__(256, 1) void nms_scan_wg(const u64* __restrict__ mask,
    int nblk, int words, u64* __restrict__ remout)
{
    __shared__ u64 rem_lds[64];
    __shared__ u64 diagS[64];
    __shared__ u64 pslot[8*64];
    int t = threadIdx.x;
    int ngrp = 256 / words;              // 36->7, 32->8
    int g = t / words, c = t % words;
    bool pactive = (g < ngrp);
    int gg = min(g, ngrp - 1);
    if (t < 64) {
        rem_lds[t] = ~0ULL;
        diagS[t] = mask[(size_t)t*words + 0];
    }
    __syncthreads();
    for (int b = 0; b < nblk; ++b) {
        const u64* blockbase = mask + (size_t)(64*b)*words;
        u64 vals[10];
        int rows[10];
        #pragma unroll
        for (int k = 0; k < 10; ++k) {
            int r = min(gg + k*ngrp, 63);
            rows[k] = r;
            vals[k] = blockbase[(size_t)r*words + c];
        }
        u64 dnext = mask[(size_t)(64*(b+1) + (t & 63))*words + min(b+1, words-1)];
        u64 mydia = diagS[t & 63];
        u64 nz = __ballot(mydia != 0ULL);
        u64 cur = rem_lds[b];
        u64 pend = cur & nz;
        unsigned mlo = (unsigned)mydia;
        unsigned mhi = (unsigned)(mydia >> 32);
        while (pend) {
            int i = __ffsll((unsigned long long)pend) - 1;
            unsigned lo = __builtin_amdgcn_readlane((int)mlo, i);
            unsigned hi = __builtin_amdgcn_readlane((int)mhi, i);
            u64 dia = ((u64)hi << 32) | lo;
            cur  &= ~dia;
            pend &= ~dia;
            pend &= pend - 1;
        }
        u64 partial = ~0ULL;
        #pragma unroll
        for (int k = 0; k < 10; ++k) {
            bool al = (cur >> rows[k]) & 1ULL;
            partial &= al ? ~vals[k] : ~0ULL;
        }
        if (pactive) pslot[g*64 + c] = partial;
        __syncthreads();
        if (t < 64) diagS[t] = dnext;
        if (t < words) {
            u64 red = rem_lds[t];
            for (int g2 = 0; g2 < ngrp; ++g2) red &= pslot[g2*64 + t];
            rem_lds[t] = red;
        }
        __syncthreads();
    }
    if (t < words) remout[t] = rem_lds[t];
}

// ============================================================
// kept-first stable selection -> proposals / valid. Also emits K (kept
// count) so downstream RoI-head kernels can skip duplicate zero-proposal
// rows (positions > K are all identical to position K's zero proposal).
// ============================================================
__global__ __launch_bounds__(256) void select_props(const u64* __restrict__ remw,
    const float4* __restrict__ sboxes, float* __restrict__ prop_out,
    float4* __restrict__ propws, int* __restrict__ validat, int* __restrict__ kcnt)
{
    __shared__ int cnt[256];
    __shared__ int pref[257];
    int t = threadIdx.x;
    int base = t*9;
    int c = 0;
    #pragma unroll
    for (int q = 0; q < 9; ++q) { int i = base+q; c += (int)((remw[i>>6]>>(i&63))&1ULL); }
    cnt[t] = c; __syncthreads();
    if (t == 0) { pref[0]=0; for (int u=0;u<256;u++) pref[u+1]=pref[u]+cnt[u]; }
    __syncthreads();
    int K = pref[256];
    if (t == 0) kcnt[0] = K;
    int kb = pref[t];
    int nb = K + (base - pref[t]);
    for (int q = 0; q < 9; ++q) {
        int i = base + q;
        int k = (int)((remw[i>>6]>>(i&63))&1ULL);
        int pos = k ? kb : nb;
        if (k) kb++; else nb++;
        if (pos < NP) {
            validat[pos] = k;
            float4 p = k ? sboxes[i] : make_float4(0.f,0.f,0.f,0.f);
            propws[pos] = p;
            prop_out[pos*4+0]=p.x; prop_out[pos*4+1]=p.y;
            prop_out[pos*4+2]=p.z; prop_out[pos*4+3]=p.w;
        }
    }
}

// ============================================================
// weight prep for 32x32x16 MFMA mask conv:
// wbt[((tap*4+kg)*2+half)*512 + oc*8 + e]  (bf16), ic = kg*16 + half*8 + e.
// ============================================================
__global__ __launch_bounds__(256) void prep_wbt(const float* __restrict__ w, u16* __restrict__ wbt)
{
    int e = blockIdx.x*256 + threadIdx.x;
    if (e >= 36864) return;
    int oc = e / 576, rem = e % 576, ic = rem / 9, tap = rem % 9;
    int kg = ic >> 4, half = (ic >> 3) & 1, el = ic & 7;
    wbt[((tap*4 + kg)*2 + half)*512 + oc*8 + el] = f2bf(w[e]);
}

// ============================================================
// K10: FUSED crop + 2x2 maxpool (-> flat, bit-exact f32) + MFMA mask head.
// Rows > K (duplicate zero proposals) are skipped; row K is the
// representative and its result is broadcast later (bit-exact).
// ============================================================
__global__ __launch_bounds__(256, 3) void mask_head_fused(const float* __restrict__ feat_tf,
    const float4* __restrict__ propws, const u16* __restrict__ wbt,
    const float* __restrict__ b_m1, const float* __restrict__ w_m2,
    const float* __restrict__ b_m2, float* __restrict__ masks_out,
    float* __restrict__ flat, const int* __restrict__ kcnt)
{
    __shared__ __align__(16) u16 crop[256*64];      // 32768 B
    __shared__ unsigned pooled[3136];               // 12544 B
    __shared__ __align__(16) int4 cidx[196];        //  3136 B
    __shared__ float2 cwt[196];                     //  1568 B
    __shared__ int2 cmeta[196];                     //  1568 B
    __shared__ __align__(16) float wm2s[64];        //   256 B
    __shared__ __align__(16) float b1s[64];         //   256 B  (total 52096)
    int n = blockIdx.x;
    if (n > *kcnt) return;
    int t = threadIdx.x;
    float4 p = propws[n];

    // zero-fill crop: lane-consecutive 16B stores, conflict-free
    #pragma unroll
    for (int k = 0; k < 8; ++k)
        *(int4*)(crop + k*2048 + t*8) = make_int4(0,0,0,0);
    for (int e = t; e < 3136; e += 256) pooled[e] = 0;
    if (t < 64) { wm2s[t] = w_m2[t]; b1s[t] = b_m1[t]; }
    if (t < 196) {
        float x1n = p.x*(1.f/255.f), y1n = p.y*(1.f/255.f);
        float x2n = p.z*(1.f/255.f), y2n = p.w*(1.f/255.f);
        int py = t / 14, px = t - py*14;
        float fyv = (y1n + (y2n-y1n)*(py*(1.f/13.f)))*15.f;
        float fxv = (x1n + (x2n-x1n)*(px*(1.f/13.f)))*15.f;
        int y0 = min(max((int)floorf(fyv),0),15), y1i = min(y0+1,15);
        int x0 = min(max((int)floorf(fxv),0),15), x1i = min(x0+1,15);
        float wy = fyv - (float)y0, wx = fxv - (float)x0;
        cidx[t] = make_int4((y0*16+x0)*64, (y0*16+x1i)*64, (y1i*16+x0)*64, (y1i*16+x1i)*64);
        cwt[t] = make_float2(wy, wx);
        cmeta[t] = make_int2((py+1)*16 + px + 1, (py>>1)*7 + (px>>1));
    }
    __syncthreads();

    int wave = t >> 6, lane = t & 63;
    for (int it = 0; it < 49; ++it) {
        int idx = it*4 + wave;                 // 0..195, wave-uniform
        int4 o4 = cidx[idx];
        float2 w2 = cwt[idx];
        int2 mt = cmeta[idx];
        float v00 = feat_tf[o4.x + lane];
        float v01 = feat_tf[o4.y + lane];
        float v10 = feat_tf[o4.z + lane];
        float v11 = feat_tf[o4.w + lane];
        float wy = w2.x, wx = w2.y;
        float top = v00*(1.f-wx) + v01*wx;
        float bot = v10*(1.f-wx) + v11*wx;
        float val = top*(1.f-wy) + bot*wy;
        int g = mt.x;
        crop[g*64 + (((lane>>3) ^ (g&7))<<3) + (lane&7)] = f2bf(val);
        atomicMax(&pooled[lane*49 + mt.y], __float_as_uint(val));
    }
    __syncthreads();

    // emit flat (bit-exact pooled max)
    {
        size_t rowoff = (size_t)n*3136;
        for (int k = t; k < 3136; k += 256)
            flat[rowoff + k] = __uint_as_float(pooled[k]);
    }

    // ---- MFMA conv: D[oc][pix], A = weights, B = crop ----
    int l31 = lane & 31, half = lane >> 5;
    int pix0 = wave*64 + l31, pix1 = pix0 + 32;

    f32x16 acc[2][2];   // [pixel tile][oc group]
    #pragma unroll
    for (int o = 0; o < 2; ++o) {
        #pragma unroll
        for (int q = 0; q < 4; ++q) {
            float4 b4 = *(const float4*)&b1s[o*32 + 4*half + 8*q];
            #pragma unroll
            for (int pp = 0; pp < 2; ++pp) {
                acc[pp][o][q*4+0] = b4.x; acc[pp][o][q*4+1] = b4.y;
                acc[pp][o][q*4+2] = b4.z; acc[pp][o][q*4+3] = b4.w;
            }
        }
    }

    for (int tap = 0; tap < 9; ++tap) {
        int doff = (tap/3 - 1)*16 + (tap%3) - 1;
        int p0 = (pix0 + doff) & 255;
        int p1 = (pix1 + doff) & 255;
        const u16* wt = wbt + tap*4096;
        bf16x8 af[2][4];
        #pragma unroll
        for (int kg = 0; kg < 4; ++kg) {
            #pragma unroll
            for (int o = 0; o < 2; ++o)
                af[o][kg] = *(const bf16x8*)(wt + (kg*2 + half)*512 + (o*32 + l31)*8);
        }
        int x0v = p0&7, x1v = p1&7;
        #pragma unroll
        for (int kg = 0; kg < 4; ++kg) {
            int slot = kg*2 + half;
            bf16x8 bf0 = *(const bf16x8*)(crop + p0*64 + ((slot ^ x0v)<<3));
            bf16x8 bf1 = *(const bf16x8*)(crop + p1*64 + ((slot ^ x1v)<<3));
            acc[0][0] = __builtin_amdgcn_mfma_f32_32x32x16_bf16(af[0][kg], bf0, acc[0][0], 0, 0, 0);
            acc[0][1] = __builtin_amdgcn_mfma_f32_32x32x16_bf16(af[1][kg], bf0, acc[0][1], 0, 0, 0);
            acc[1][0] = __builtin_amdgcn_mfma_f32_32x32x16_bf16(af[0][kg], bf1, acc[1][0], 0, 0, 0);
            acc[1][1] = __builtin_amdgcn_mfma_f32_32x32x16_bf16(af[1][kg], bf1, acc[1][1], 0, 0, 0);
        }
    }

    // ---- epilogue: relu, * w_m2[oc], sum over 64 oc, + b_m2 ----
    float4 wmq[2][4];
    #pragma unroll
    for (int o = 0; o < 2; ++o)
        #pragma unroll
        for (int q = 0; q < 4; ++q)
            wmq[o][q] = *(const float4*)&wm2s[o*32 + 4*half + 8*q];
    float s0 = 0.f, s1 = 0.f;
    #pragma unroll
    for (int o = 0; o < 2; ++o) {
        #pragma unroll
        for (int q = 0; q < 4; ++q) {
            float4 w4 = wmq[o][q];
            s0 = fmaf(fmaxf(acc[0][o][q*4+0], 0.f), w4.x, s0);
            s0 = fmaf(fmaxf(acc[0][o][q*4+1], 0.f), w4.y, s0);
            s0 = fmaf(fmaxf(acc[0][o][q*4+2], 0.f), w4.z, s0);
            s0 = fmaf(fmaxf(acc[0][o][q*4+3], 0.f), w4.w, s0);
            s1 = fmaf(fmaxf(acc[1][o][q*4+0], 0.f), w4.x, s1);
            s1 = fmaf(fmaxf(acc[1][o][q*4+1], 0.f), w4.y, s1);
            s1 = fmaf(fmaxf(acc[1][o][q*4+2], 0.f), w4.z, s1);
            s1 = fmaf(fmaxf(acc[1][o][q*4+3], 0.f), w4.w, s1);
        }
    }
    s0 += __shfl_xor(s0, 32);
    s1 += __shfl_xor(s1, 32);
    float sv = (half ? s1 : s0) + b_m2[0];
    int pw = half ? pix1 : pix0;
    int pyy = (pw>>4) - 1, pxx = (pw&15) - 1;
    if ((unsigned)pyy < 14u && (unsigned)pxx < 14u)
        masks_out[(size_t)n*196 + pyy*14 + pxx] = sv;
}

// ============================================================
// broadcast row K's RoI-head results into duplicate rows K+1..NP-1.
// Bit-exact: those rows have identical inputs (zero proposal).
// ============================================================
__global__ __launch_bounds__(256) void bcast_rows(const int* __restrict__ kcnt,
    float* __restrict__ out_logits, float* __restrict__ out_deltas,
    float* __restrict__ masks_out, float4* __restrict__ dets,
    float* __restrict__ dscores, float* __restrict__ s2)
{
    int K = *kcnt;
    int j = blockIdx.x;
    if (j <= K) return;
    int t = threadIdx.x;
    if (t < 196) {
        masks_out[(size_t)j*196 + t] = masks_out[(size_t)K*196 + t];
    } else if (t == 196) {
        out_logits[j*2+0] = out_logits[K*2+0];
        out_logits[j*2+1] = out_logits[K*2+1];
    } else if (t == 197) {
        out_deltas[j*4+0] = out_deltas[K*4+0];
        out_deltas[j*4+1] = out_deltas[K*4+1];
        out_deltas[j*4+2] = out_deltas[K*4+2];
        out_deltas[j*4+3] = out_deltas[K*4+3];
    } else if (t == 198) {
        dets[j] = dets[K];
        dscores[j] = dscores[K];
        s2[j] = s2[K];
    }
}

// ============================================================
// f32 GEMM partial over K-split — single-wave 32x32 tile, 64 threads,
// BK=32 (proven best across 5 structural variants). NAMED prefetch
// registers only (float4 arrays demote to scratch). XCD-aware tile
// swizzle: launch-id%8 selects a col-pair per XCD (bijective remap,
// gridDim.y=16; z-stride 1008 % 8 == 0 keeps mapping per K-split).
// k strictly ascending per output -> partials bit-identical.
// Row tiles above kcnt exit (duplicate rows).
// ============================================================
__global__ __launch_bounds__(64) void gemm_f32_w1(const float* __restrict__ A,
    const float* __restrict__ B, float* __restrict__ Cpart,
    int M, int N, int K, int Kblk, const int* __restrict__ kcnt)
{
    int flat = blockIdx.x + blockIdx.y*gridDim.x;       // launch order, x fastest
    int colt = ((flat & 7) << 1) | ((flat >> 3) & 1);   // 16 cols, 2 per XCD
    int rowt = flat >> 4;                               // 0..62
    int row0 = rowt*32, col0 = colt*32;
    if (row0 > *kcnt) return;
    __shared__ __align__(16) float As[32][36];
    __shared__ __align__(16) float Bs[32][36];
    int s = blockIdx.z;
    int kbase = s*Kblk;
    int t = threadIdx.x;

    // staging maps (64 threads)
    int arow = t >> 1;            // 0..31
    int kh   = (t & 1) * 16;      // 0 or 16
    int am = min(row0 + arow, M-1);
    const float* Arow = A + (size_t)am*K + kbase + kh;
    int bk = t & 31;              // 0..31
    int ch = (t >> 5) * 16;       // 0 or 16
    const float* Bbase = B + (size_t)(kbase + bk)*N + col0 + ch;

    // compute map: 8x8 lane grid, 4x4 outputs each
    int cx = t & 7, ry = (t >> 3) & 7;
    int rbase = ry*4, cbase = cx*4;

    float4 pa0 = *(const float4*)(Arow);
    float4 pa1 = *(const float4*)(Arow + 4);
    float4 pa2 = *(const float4*)(Arow + 8);
    float4 pa3 = *(const float4*)(Arow + 12);
    float4 pb0 = *(const float4*)(Bbase);
    float4 pb1 = *(const float4*)(Bbase + 4);
    float4 pb2 = *(const float4*)(Bbase + 8);
    float4 pb3 = *(const float4*)(Bbase + 12);

    float acc[4][4] = {};
    for (int k0 = 0; k0 < Kblk; k0 += 32) {
        As[kh+ 0][arow]=pa0.x; As[kh+ 1][arow]=pa0.y; As[kh+ 2][arow]=pa0.z; As[kh+ 3][arow]=pa0.w;
        As[kh+ 4][arow]=pa1.x; As[kh+ 5][arow]=pa1.y; As[kh+ 6][arow]=pa1.z; As[kh+ 7][arow]=pa1.w;
        As[kh+ 8][arow]=pa2.x; As[kh+ 9][arow]=pa2.y; As[kh+10][arow]=pa2.z; As[kh+11][arow]=pa2.w;
        As[kh+12][arow]=pa3.x; As[kh+13][arow]=pa3.y; As[kh+14][arow]=pa3.z; As[kh+15][arow]=pa3.w;
        *(float4*)&Bs[bk][ch]    = pb0;
        *(float4*)&Bs[bk][ch+4]  = pb1;
        *(float4*)&Bs[bk][ch+8]  = pb2;
        *(float4*)&Bs[bk][ch+12] = pb3;
        __syncthreads();
        int kn = k0 + 32;
        if (kn < Kblk) {
            pa0 = *(const float4*)(Arow + kn);
            pa1 = *(const float4*)(Arow + kn + 4);
            pa2 = *(const float4*)(Arow + kn + 8);
            pa3 = *(const float4*)(Arow + kn + 12);
            const float* Bn = Bbase + (size_t)kn*N;
            pb0 = *(const float4*)(Bn);
            pb1 = *(const float4*)(Bn + 4);
            pb2 = *(const float4*)(Bn + 8);
            pb3 = *(const float4*)(Bn + 12);
        }
        #pragma unroll
        for (int k = 0; k < 32; ++k) {
            float4 av = *(float4*)&As[k][rbase];
            float4 bv = *(float4*)&Bs[k][cbase];
            float a_[4] = {av.x, av.y, av.z, av.w};
            float b_[4] = {bv.x, bv.y, bv.z, bv.w};
            #pragma unroll
            for (int i = 0; i < 4; ++i)
                #pragma unroll
                for (int j = 0; j < 4; ++j)
                    acc[i][j] = fmaf(a_[i], b_[j], acc[i][j]);
        }
        __syncthreads();
    }
    float* Cp = Cpart + (size_t)s*M*N;
    #pragma unroll
    for (int i = 0; i < 4; ++i) {
        int gm = row0 + rbase + i;
        if (gm >= M) continue;
        #pragma unroll
        for (int j = 0; j < 4; ++j) {
            int gn = col0 + cbase + j;
            Cp[(size_t)gm*N + gn] = acc[i][j];
        }
    }
}

// ============================================================
// combine K-split partials in ascending-s order + bias + optional relu.
// Rows above kcnt skipped (duplicate rows, never consumed).
// ============================================================
__global__ __launch_bounds__(256) void combine_parts(const float* __restrict__ parts,
    const float* __restrict__ bias, float* __restrict__ C,
    int MN, int N, int S, int relu, const int* __restrict__ kcnt)
{
    int i4 = blockIdx.x*256 + threadIdx.x;
    if (i4*4 >= MN) return;
    size_t idx = (size_t)i4*4;
    if ((int)(idx / (unsigned)N) > *kcnt) return;
    float4 acc = *(const float4*)(parts + idx);
    for (int s = 1; s < S; ++s) {
        float4 v = *(const float4*)(parts + (size_t)s*MN + idx);
        acc.x += v.x; acc.y += v.y; acc.z += v.z; acc.w += v.w;
    }
    int nb = (int)(idx & (N-1));
    float4 bv = *(const float4*)(bias + nb);
    acc.x += bv.x; acc.y += bv.y; acc.z += bv.z; acc.w += bv.w;
    if (relu) {
        acc.x = fmaxf(acc.x, 0.f); acc.y = fmaxf(acc.y, 0.f);
        acc.z = fmaxf(acc.z, 0.f); acc.w = fmaxf(acc.w, 0.f);
    }
    *(float4*)(C + idx) = acc;
}

// ============================================================
// K9: rcnn heads — coalesced LDS staging, then 8 serial threads replay
// the sequential fmaf chain bit-exactly. Blocks fully above kcnt skip.
// ============================================================
__global__ __launch_bounds__(256) void rcnn_heads_lds(const float* __restrict__ h2,
    const float* __restrict__ w_rcls, const float* __restrict__ b_rcls,
    const float* __restrict__ w_rbox, const float* __restrict__ b_rbox,
    const float4* __restrict__ propws, const int* __restrict__ validat,
    float* __restrict__ out_logits, float* __restrict__ out_deltas,
    float4* __restrict__ dets, float* __restrict__ dscores, float* __restrict__ s2,
    const int* __restrict__ kcnt)
{
    int b0 = blockIdx.x*8;
    if (b0 > *kcnt) return;
    __shared__ float hs[8*520];
    for (int e = threadIdx.x; e < 8*512; e += 256) {
        int pr = e >> 9, k = e & 511;
        hs[pr*520 + k] = h2[(size_t)(b0+pr)*512 + k];
    }
    __syncthreads();
    int t = threadIdx.x;
    if (t >= 8) return;
    int n = b0 + t;
    const float* hv = hs + t*520;
    float l0 = b_rcls[0], l1 = b_rcls[1];
    float d0 = b_rbox[0], d1 = b_rbox[1], d2 = b_rbox[2], d3 = b_rbox[3];
    for (int k = 0; k < 512; ++k) {
        float v = hv[k];
        l0 = fmaf(v, w_rcls[k*2+0], l0); l1 = fmaf(v, w_rcls[k*2+1], l1);
        d0 = fmaf(v, w_rbox[k*4+0], d0); d1 = fmaf(v, w_rbox[k*4+1], d1);
        d2 = fmaf(v, w_rbox[k*4+2], d2); d3 = fmaf(v, w_rbox[k*4+3], d3);
    }
    out_logits[n*2+0]=l0; out_logits[n*2+1]=l1;
    out_deltas[n*4+0]=d0; out_deltas[n*4+1]=d1;
    out_deltas[n*4+2]=d2; out_deltas[n*4+3]=d3;
    float mx = fmaxf(l0,l1);
    float e0 = expf(l0-mx), e1 = expf(l1-mx);
    float sc = e1/(e0+e1);
    float4 p = propws[n];
    float w = p.z-p.x, h = p.w-p.y;
    float cx = p.x + 0.5f*w, cy = p.y + 0.5f*h;
    float ncx = cx + d0*w, ncy = cy + d1*h;
    float nw = w*expf(d2), nh = h*expf(d3);
    float x1 = ncx-0.5f*nw, y1 = ncy-0.5f*nh, x2 = ncx+0.5f*nw, y2 = ncy+0.5f*nh;
    const float lim = 255.f;
    x1 = fminf(fmaxf(x1,0.f),lim); y1 = fminf(fmaxf(y1,0.f),lim);
    x2 = fminf(fmaxf(x2,0.f),lim); y2 = fminf(fmaxf(y2,0.f),lim);
    dets[n] = make_float4(x1,y1,x2,y2);
    dscores[n] = sc;
    s2[n] = validat[n] ? sc : -1.0f;
}

// ============================================================
// final outputs
// ============================================================
__global__ void finalize(const u64* __restrict__ remw2,
    const int* __restrict__ order2, const int* __restrict__ validat,
    const float4* __restrict__ dets, const float* __restrict__ dscores,
    const float* __restrict__ masks_in, float* __restrict__ fdets,
    float* __restrict__ fscores, float* __restrict__ fmasks, float* __restrict__ keep2out)
{
    int j = blockIdx.x;
    int t = threadIdx.x;
    int o = order2[j];
    int kb = (int)((remw2[j>>6] >> (j&63)) & 1ULL);
    int k2 = kb & validat[o];
    if (t == 0) {
        float4 d = dets[o];
        if (!k2) d = make_float4(0.f,0.f,0.f,0.f);
        fdets[j*4+0]=d.x; fdets[j*4+1]=d.y; fdets[j*4+2]=d.z; fdets[j*4+3]=d.w;
        fscores[j] = k2 ? dscores[o] : 0.f;
        keep2out[j] = (float)k2;
    }
    if (t < 196) {
        float mv = masks_in[(size_t)o*196 + t];
        float sg = 1.f/(1.f + expf(-mv));
        fmasks[(size_t)j*196 + t] = k2 ? sg : 0.f;
    }
}

// ============================================================
extern "C" void kernel_launch(void* const* d_in, const int* in_sizes, int n_in,
                              void* d_out, int out_size, void* d_ws, size_t ws_size,
                              hipStream_t stream)
{
    const float* x      = (const float*)d_in[0];
    const float* w_bb   = (const float*)d_in[1];
    const float* b_bb   = (const float*)d_in[2];
    const float* w_rpn  = (const float*)d_in[3];
    const float* b_rpn  = (const float*)d_in[4];
    const float* w_cls  = (const float*)d_in[5];
    const float* b_cls  = (const float*)d_in[6];
    const float* w_box  = (const float*)d_in[7];
    const float* b_box  = (const float*)d_in[8];
    const float* w_fc1  = (const float*)d_in[9];
    const float* b_fc1  = (const float*)d_in[10];
    const float* w_fc2  = (const float*)d_in[11];
    const float* b_fc2  = (const float*)d_in[12];
    const float* w_rcls = (const float*)d_in[13];
    const float* b_rcls = (const float*)d_in[14];
    const float* w_rbox = (const float*)d_in[15];
    const float* b_rbox = (const float*)d_in[16];
    const float* w_m1   = (const float*)d_in[17];
    const float* b_m1   = (const float*)d_in[18];
    const float* w_m2   = (const float*)d_in[19];
    const float* b_m2   = (const float*)d_in[20];

    float* out = (float*)d_out;

    // ---- workspace carve-up (256B-aligned chunks) ----
    char* basep = (char*)d_ws;
    auto alloc = [&](size_t bytes) { char* q = basep; basep += (bytes + 255) & ~(size_t)255; return q; };
    float* feat    = (float*)alloc(16384*4);
    float* feat_tf = (float*)alloc(16384*4);
    float* hbuf    = (float*)alloc(16384*4);
    float* scores  = (float*)alloc(2304*4);
    float* boxes   = (float*)alloc(9216*4);
    int*   order1  = (int*)  alloc(2304*4);
    int*   rparts  = (int*)  alloc((size_t)9*2304*4);
    float* sboxes  = (float*)alloc(9216*4);
    float* sareas  = (float*)alloc(2304*4);
    u64*   supm1   = (u64*)  alloc((size_t)((W1+1)*64)*W1*8);   // +64 slack rows
    u64*   remw1   = (u64*)  alloc(W1*8);
    int*   validat = (int*)  alloc(NP*4);
    float* propws  = (float*)alloc(NP*4*4);
    int*   kcnt    = (int*)  alloc(4);
    u16*   wbt     = (u16*)  alloc(36864*2);
    float* flat    = (float*)alloc((size_t)NP*3136*4);
    float* h1      = (float*)alloc((size_t)NP*512*4);
    float* h2      = (float*)alloc((size_t)NP*512*4);
    float* gparts  = (float*)alloc((size_t)7*NP*512*4);     // K-split partials
    float* dets    = (float*)alloc(NP*4*4);
    float* dscores = (float*)alloc(NP*4);
    float* s2      = (float*)alloc(NP*4);
    int*   order2  = (int*)  alloc(NP*4);
    float* sdets   = (float*)alloc(NP*4*4);
    float* sareas2 = (float*)alloc(NP*4);
    u64*   supm2   = (u64*)  alloc((size_t)((W2+1)*64)*W2*8);   // +64 slack rows
    u64*   remw2   = (u64*)  alloc(W2*8);

    // ---- stage 1: backbone + rpn ----
    bb_conv<<<64, 256, 0, stream>>>(x, w_bb, b_bb, feat, feat_tf);
    rpn_conv<<<64, 256, 0, stream>>>(feat, w_rpn, b_rpn, hbuf);
    heads_rpn<<<9, 256, 0, stream>>>(hbuf, w_cls, b_cls, w_box, b_box,
        out + O_RPN_LOGITS, out + O_RPN_DELTAS, out + O_ANCHORS, scores, boxes);

    // ---- NMS 1 ----
    rank_part<<<dim3(9, 9), 256, 0, stream>>>(scores, rparts, N_ANCH);
    rank_scatter<<<9, 256, 0, stream>>>(rparts, order1, N_ANCH, 9);
    gather_sorted<<<9, 256, 0, stream>>>((const float4*)boxes, order1,
                                         (float4*)sboxes, sareas, N_ANCH);
    iou_mask<<<(W1*64*W1+255)/256, 256, 0, stream>>>((const float4*)sboxes, sareas,
                                                     N_ANCH, W1*64, W1, 0.5f, supm1);
    nms_scan_wg<<<1, 256, 0, stream>>>(supm1, W1, W1, remw1);
    select_props<<<1, 256, 0, stream>>>(remw1, (const float4*)sboxes,
                                        out + O_PROPOSALS, (float4*)propws, validat, kcnt);

    // ---- weight prep (independent of NMS; early) ----
    prep_wbt<<<144, 256, 0, stream>>>(w_m1, wbt);

    // ---- RoI head: fused crop+pool+mask first (produces flat) ----
    mask_head_fused<<<NP, 256, 0, stream>>>(feat_tf, (const float4*)propws, wbt,
        b_m1, w_m2, b_m2, out + O_RCNN_MASKS, flat, kcnt);
    // fc1: K=3136 split 7 x 448; single-wave 32x32 tiles, BK=32 + XCD swizzle
    gemm_f32_w1<<<dim3(63, 16, 7), 64, 0, stream>>>(flat, w_fc1, gparts,
                                                    NP, 512, 3136, 448, kcnt);
    combine_parts<<<(NP*512/4+255)/256, 256, 0, stream>>>(gparts, b_fc1, h1,
                                                          NP*512, 512, 7, 1, kcnt);
    // fc2: K=512 split 2 x 256
    gemm_f32_w1<<<dim3(63, 16, 2), 64, 0, stream>>>(h1, w_fc2, gparts,
                                                    NP, 512, 512, 256, kcnt);
    combine_parts<<<(NP*512/4+255)/256, 256, 0, stream>>>(gparts, b_fc2, h2,
                                                          NP*512, 512, 2, 1, kcnt);
    rcnn_heads_lds<<<250, 256, 0, stream>>>(h2, w_rcls, b_rcls, w_rbox, b_rbox,
        (const float4*)propws, validat, out + O_RCNN_LOGITS, out + O_RCNN_DELTAS,
        (float4*)dets, dscores, s2, kcnt);

    // ---- broadcast duplicate rows (bit-exact) before NMS2 consumes them ----
    bcast_rows<<<NP, 256, 0, stream>>>(kcnt, out + O_RCNN_LOGITS, out + O_RCNN_DELTAS,
        out + O_RCNN_MASKS, (float4*)dets, dscores, s2);

    // ---- NMS 2 + finalize ----
    rank_part<<<dim3(8, 8), 256, 0, stream>>>(s2, rparts, NP);
    rank_scatter<<<8, 256, 0, stream>>>(rparts, order2, NP, 8);
    gather_sorted<<<8, 256, 0, stream>>>((const float4*)dets, order2,
                                         (float4*)sdets, sareas2, NP);
    iou_mask<<<(W2*64*W2+255)/256, 256, 0, stream>>>((const float4*)sdets, sareas2,
                                                     NP, W2*64, W2, 0.3f, supm2);
    nms_scan_wg<<<1, 256, 0, stream>>>(supm2, W2, W2, remw2);
    finalize<<<NP, 256, 0, stream>>>(remw2, order2, validat, (const float4*)dets,
        dscores, out + O_RCNN_MASKS, out + O_FINAL_DETS, out + O_FINAL_SCORES,
        out + O_FINAL_MASKS, out + O_KEEP2);
}